// Round 11
// baseline (25.790 us; speedup 1.0000x reference)
//
#include <hip/hip_runtime.h>

// DiceLoss: input (B=16, C=4, H=512, W=512) f32, target (B,H,W) int32.
// pred = argmax_c input; per class c: pp=#pred==c, tt=#tgt==c, ii=#(pred==c & tgt==c).
// loss = mean_c (1 - (2*ii+eps)/(pp+tt+eps)).
//
// R11: two-kernel structure (best at 21.8; fused R10 ties at 22.7).
// Count kernel layout change: each thread reads 16 CONTIGUOUS pixels
// (4 successive float4 per class plane + 4 int4 target) -> per wave
// 5 streams x 4KiB contiguous instead of 20 x 1KiB scattered across 64MiB.
// Tests whether per-wave DRAM page locality is what caps read BW at ~5.3 TB/s
// (MLP depth, occupancy, VALU all exonerated in R5/R6/R8).

static constexpr int kHW     = 512 * 512;       // 262144
static constexpr int kC      = 4;
static constexpr int kBlocks  = 1024;
static constexpr int kThreads = 256;
static constexpr float kEps = 1e-6f;

__device__ __forceinline__ void quad_count(
    const float4& c0, const float4& c1, const float4& c2, const float4& c3,
    const int4& t4, unsigned int& pp, unsigned int& tt, unsigned int& ii)
{
    const float a0[4] = {c0.x, c0.y, c0.z, c0.w};
    const float a1[4] = {c1.x, c1.y, c1.z, c1.w};
    const float a2[4] = {c2.x, c2.y, c2.z, c2.w};
    const float a3[4] = {c3.x, c3.y, c3.z, c3.w};
    const int   tv[4] = {t4.x, t4.y, t4.z, t4.w};
#pragma unroll
    for (int j = 0; j < 4; ++j) {
        int pred = 0; float bv = a0[j];
        if (a1[j] > bv) { bv = a1[j]; pred = 1; }
        if (a2[j] > bv) { bv = a2[j]; pred = 2; }
        if (a3[j] > bv) { bv = a3[j]; pred = 3; }
        const int t = tv[j];
        pp += 1u << (pred << 3);
        tt += 1u << (t << 3);
        ii += (unsigned int)(pred == t) << (t << 3);
    }
}

// partials layout: partial[c * kBlocks + blk], c in [0,12)
__global__ __launch_bounds__(kThreads, 4) void dice_count_kernel(
    const float* __restrict__ in, const int* __restrict__ tgt,
    unsigned int* __restrict__ partial)
{
    const int tid = blockIdx.x * kThreads + threadIdx.x;

    // thread handles 16 consecutive pixels [p0, p0+16) - all in one batch
    // (16 divides kHW so no batch crossing). b = tid >> 14, hw = (tid*16) & (kHW-1).
    const int p0 = tid << 4;
    const int b  = tid >> 14;
    const int hw = p0 & (kHW - 1);
    const float* base = in + (size_t)b * (kC * kHW) + hw;

    // 20 loads, 5 contiguous 64B streams per thread, issued before consumption
    const float4 A0 = *(const float4*)(base);
    const float4 A1 = *(const float4*)(base + 4);
    const float4 A2 = *(const float4*)(base + 8);
    const float4 A3 = *(const float4*)(base + 12);
    const float4 B0 = *(const float4*)(base + kHW);
    const float4 B1 = *(const float4*)(base + kHW + 4);
    const float4 B2 = *(const float4*)(base + kHW + 8);
    const float4 B3 = *(const float4*)(base + kHW + 12);
    const float4 C0 = *(const float4*)(base + 2 * kHW);
    const float4 C1 = *(const float4*)(base + 2 * kHW + 4);
    const float4 C2 = *(const float4*)(base + 2 * kHW + 8);
    const float4 C3 = *(const float4*)(base + 2 * kHW + 12);
    const float4 D0 = *(const float4*)(base + 3 * kHW);
    const float4 D1 = *(const float4*)(base + 3 * kHW + 4);
    const float4 D2 = *(const float4*)(base + 3 * kHW + 8);
    const float4 D3 = *(const float4*)(base + 3 * kHW + 12);
    const int4   T0 = *(const int4*)(tgt + p0);
    const int4   T1 = *(const int4*)(tgt + p0 + 4);
    const int4   T2 = *(const int4*)(tgt + p0 + 8);
    const int4   T3 = *(const int4*)(tgt + p0 + 12);

    unsigned int pp = 0, tt = 0, ii = 0;   // byte-packed; 16 pixels/thread per field
    // pixel j of chunk k: classes are A_k..D_k components (A=class0 ... D=class3)
    quad_count(A0, B0, C0, D0, T0, pp, tt, ii);
    quad_count(A1, B1, C1, D1, T1, pp, tt, ii);
    quad_count(A2, B2, C2, D2, T2, pp, tt, ii);
    quad_count(A3, B3, C3, D3, T3, pp, tt, ii);

    // packed butterfly over 8 lanes (fields reach 16*8=128 < 256: no overflow)
#pragma unroll
    for (int o = 1; o <= 4; o <<= 1) {
        pp += __shfl_xor(pp, o, 64);
        tt += __shfl_xor(tt, o, 64);
        ii += __shfl_xor(ii, o, 64);
    }

    // unpack, finish wave reduction at offsets 8/16/32
    unsigned int loc[12];
#pragma unroll
    for (int c = 0; c < 4; ++c) {
        loc[c]     = (pp >> (c * 8)) & 0xFF;
        loc[4 + c] = (tt >> (c * 8)) & 0xFF;
        loc[8 + c] = (ii >> (c * 8)) & 0xFF;
    }
#pragma unroll
    for (int i = 0; i < 12; ++i) {
        loc[i] += __shfl_xor(loc[i], 8, 64);
        loc[i] += __shfl_xor(loc[i], 16, 64);
        loc[i] += __shfl_xor(loc[i], 32, 64);
    }

    // block reduction across 4 waves
    __shared__ unsigned int s[4][12];
    const int wave = threadIdx.x >> 6;
    if ((threadIdx.x & 63) == 0) {
#pragma unroll
        for (int i = 0; i < 12; ++i) s[wave][i] = loc[i];
    }
    __syncthreads();
    if (threadIdx.x < 12) {
        partial[threadIdx.x * kBlocks + blockIdx.x] =
            s[0][threadIdx.x] + s[1][threadIdx.x] + s[2][threadIdx.x] + s[3][threadIdx.x];
    }
}

__global__ __launch_bounds__(256, 4) void dice_final_kernel(
    const unsigned int* __restrict__ partial, float* __restrict__ out)
{
    const int t = threadIdx.x;
    unsigned int loc[12];

    // one uint4 per class per thread: 12 independent coalesced 16B loads,
    // 256 threads x 4 = 1024 partials per class (exact)
#pragma unroll
    for (int c = 0; c < 12; ++c) {
        const uint4 u = *(const uint4*)(partial + c * kBlocks + t * 4);
        loc[c] = u.x + u.y + u.z + u.w;
    }

#pragma unroll
    for (int i = 0; i < 12; ++i) {
#pragma unroll
        for (int o = 1; o <= 32; o <<= 1) loc[i] += __shfl_xor(loc[i], o, 64);
    }

    __shared__ unsigned int s[4][12];
    const int wave = t >> 6;
    if ((t & 63) == 0) {
#pragma unroll
        for (int i = 0; i < 12; ++i) s[wave][i] = loc[i];
    }
    __syncthreads();

    if (t == 0) {
        float loss = 0.0f;
#pragma unroll
        for (int c = 0; c < kC; ++c) {
            const float ppc = (float)(s[0][c] + s[1][c] + s[2][c] + s[3][c]);
            const float ttc = (float)(s[0][4+c] + s[1][4+c] + s[2][4+c] + s[3][4+c]);
            const float iic = (float)(s[0][8+c] + s[1][8+c] + s[2][8+c] + s[3][8+c]);
            loss += 1.0f - (2.0f * iic + kEps) / (ppc + ttc + kEps);
        }
        out[0] = loss * 0.25f;
    }
}

extern "C" void kernel_launch(void* const* d_in, const int* in_sizes, int n_in,
                              void* d_out, int out_size, void* d_ws, size_t ws_size,
                              hipStream_t stream) {
    const float* in  = (const float*)d_in[0];
    const int*   tgt = (const int*)d_in[1];
    float* out = (float*)d_out;
    unsigned int* partial = (unsigned int*)d_ws;  // 12 * kBlocks uints = 48 KiB

    dice_count_kernel<<<kBlocks, kThreads, 0, stream>>>(in, tgt, partial);
    dice_final_kernel<<<1, 256, 0, stream>>>(partial, out);
}

// Round 12
// 22.084 us; speedup vs baseline: 1.1678x; 1.1678x over previous
//
#include <hip/hip_runtime.h>

// DiceLoss: input (B=16, C=4, H=512, W=512) f32, target (B,H,W) int32.
// pred = argmax_c input; per class c: pp=#pred==c, tt=#tgt==c, ii=#(pred==c & tgt==c).
// loss = mean_c (1 - (2*ii+eps)/(pp+tt+eps)).
//
// FINAL (revert to R6, best measured 21.8us):
// - Two dispatches. Fusion tested 4x (R4/R7/R9/R10): fences cost +23us
//   (per-block L2 writeback), single-ticket chain +10us, fenceless ticket
//   tree ties (22.7) but never wins - the saved launch is spent on tail+sc1.
// - Count kernel: lane-coalesced float4 streams (R11's contiguous-per-thread
//   variant degraded per-instruction coalescing 4x -> 25.8us). 20 loads in
//   flight/thread (R5->R6 +0.5us), 1024 blocks (2048 neutral, R8).
// - Count body ~15.5us for 84MB = 5.4 TB/s = 86% of 6.3 TB/s achievable D2D;
//   VALUBusy ~4%, bank conflicts 0. Residual = final kernel + launch overhead.

static constexpr int kHW     = 512 * 512;       // 262144
static constexpr int kC      = 4;
static constexpr int kBlocks  = 1024;
static constexpr int kThreads = 256;
static constexpr float kEps = 1e-6f;

__device__ __forceinline__ void quad_count(
    const float4& c0, const float4& c1, const float4& c2, const float4& c3,
    const int4& t4, unsigned int& pp, unsigned int& tt, unsigned int& ii)
{
    const float a0[4] = {c0.x, c0.y, c0.z, c0.w};
    const float a1[4] = {c1.x, c1.y, c1.z, c1.w};
    const float a2[4] = {c2.x, c2.y, c2.z, c2.w};
    const float a3[4] = {c3.x, c3.y, c3.z, c3.w};
    const int   tv[4] = {t4.x, t4.y, t4.z, t4.w};
#pragma unroll
    for (int j = 0; j < 4; ++j) {
        int pred = 0; float bv = a0[j];
        if (a1[j] > bv) { bv = a1[j]; pred = 1; }
        if (a2[j] > bv) { bv = a2[j]; pred = 2; }
        if (a3[j] > bv) { bv = a3[j]; pred = 3; }
        const int t = tv[j];
        pp += 1u << (pred << 3);
        tt += 1u << (t << 3);
        ii += (unsigned int)(pred == t) << (t << 3);
    }
}

// partials layout: partial[c * kBlocks + blk], c in [0,12)
__global__ __launch_bounds__(kThreads, 4) void dice_count_kernel(
    const float* __restrict__ in, const int* __restrict__ tgt,
    unsigned int* __restrict__ partial)
{
    const int tid = blockIdx.x * kThreads + threadIdx.x;

    // quad i covers pixel p_i = tid*4 + i*2^20: same hw for all i, b = b0 + 4i.
    const int p0 = tid << 2;
    const int b0 = p0 >> 18;
    const int hw = p0 & (kHW - 1);
    const float* baseA = in + (size_t)b0 * (kC * kHW) + hw;   // batches b0, b0+4, b0+8, b0+12
    const float* baseB = baseA + (size_t)4 * kC * kHW;
    const float* baseC = baseB + (size_t)4 * kC * kHW;
    const float* baseD = baseC + (size_t)4 * kC * kHW;

    // single batch: all 20 loads issued before any consumption
    const float4 A0 = *(const float4*)(baseA);
    const float4 A1 = *(const float4*)(baseA + kHW);
    const float4 A2 = *(const float4*)(baseA + 2 * kHW);
    const float4 A3 = *(const float4*)(baseA + 3 * kHW);
    const float4 B0 = *(const float4*)(baseB);
    const float4 B1 = *(const float4*)(baseB + kHW);
    const float4 B2 = *(const float4*)(baseB + 2 * kHW);
    const float4 B3 = *(const float4*)(baseB + 3 * kHW);
    const float4 C0 = *(const float4*)(baseC);
    const float4 C1 = *(const float4*)(baseC + kHW);
    const float4 C2 = *(const float4*)(baseC + 2 * kHW);
    const float4 C3 = *(const float4*)(baseC + 3 * kHW);
    const float4 D0 = *(const float4*)(baseD);
    const float4 D1 = *(const float4*)(baseD + kHW);
    const float4 D2 = *(const float4*)(baseD + 2 * kHW);
    const float4 D3 = *(const float4*)(baseD + 3 * kHW);
    const int4   TA = *(const int4*)(tgt + p0);
    const int4   TB = *(const int4*)(tgt + p0 + (1 << 20));
    const int4   TC = *(const int4*)(tgt + p0 + (2 << 20));
    const int4   TD = *(const int4*)(tgt + p0 + (3 << 20));

    unsigned int pp = 0, tt = 0, ii = 0;   // byte-packed; 16 pixels/thread per field
    quad_count(A0, A1, A2, A3, TA, pp, tt, ii);
    quad_count(B0, B1, B2, B3, TB, pp, tt, ii);
    quad_count(C0, C1, C2, C3, TC, pp, tt, ii);
    quad_count(D0, D1, D2, D3, TD, pp, tt, ii);

    // packed butterfly over 8 lanes (fields reach 16*8=128 < 256: no overflow)
#pragma unroll
    for (int o = 1; o <= 4; o <<= 1) {
        pp += __shfl_xor(pp, o, 64);
        tt += __shfl_xor(tt, o, 64);
        ii += __shfl_xor(ii, o, 64);
    }

    // unpack, finish wave reduction at offsets 8/16/32
    unsigned int loc[12];
#pragma unroll
    for (int c = 0; c < 4; ++c) {
        loc[c]     = (pp >> (c * 8)) & 0xFF;
        loc[4 + c] = (tt >> (c * 8)) & 0xFF;
        loc[8 + c] = (ii >> (c * 8)) & 0xFF;
    }
#pragma unroll
    for (int i = 0; i < 12; ++i) {
        loc[i] += __shfl_xor(loc[i], 8, 64);
        loc[i] += __shfl_xor(loc[i], 16, 64);
        loc[i] += __shfl_xor(loc[i], 32, 64);
    }

    // block reduction across 4 waves
    __shared__ unsigned int s[4][12];
    const int wave = threadIdx.x >> 6;
    if ((threadIdx.x & 63) == 0) {
#pragma unroll
        for (int i = 0; i < 12; ++i) s[wave][i] = loc[i];
    }
    __syncthreads();
    if (threadIdx.x < 12) {
        partial[threadIdx.x * kBlocks + blockIdx.x] =
            s[0][threadIdx.x] + s[1][threadIdx.x] + s[2][threadIdx.x] + s[3][threadIdx.x];
    }
}

__global__ __launch_bounds__(256, 4) void dice_final_kernel(
    const unsigned int* __restrict__ partial, float* __restrict__ out)
{
    const int t = threadIdx.x;
    unsigned int loc[12];

    // one uint4 per class per thread: 12 independent coalesced 16B loads,
    // 256 threads x 4 = 1024 partials per class (exact)
#pragma unroll
    for (int c = 0; c < 12; ++c) {
        const uint4 u = *(const uint4*)(partial + c * kBlocks + t * 4);
        loc[c] = u.x + u.y + u.z + u.w;
    }

#pragma unroll
    for (int i = 0; i < 12; ++i) {
#pragma unroll
        for (int o = 1; o <= 32; o <<= 1) loc[i] += __shfl_xor(loc[i], o, 64);
    }

    __shared__ unsigned int s[4][12];
    const int wave = t >> 6;
    if ((t & 63) == 0) {
#pragma unroll
        for (int i = 0; i < 12; ++i) s[wave][i] = loc[i];
    }
    __syncthreads();

    if (t == 0) {
        float loss = 0.0f;
#pragma unroll
        for (int c = 0; c < kC; ++c) {
            const float ppc = (float)(s[0][c] + s[1][c] + s[2][c] + s[3][c]);
            const float ttc = (float)(s[0][4+c] + s[1][4+c] + s[2][4+c] + s[3][4+c]);
            const float iic = (float)(s[0][8+c] + s[1][8+c] + s[2][8+c] + s[3][8+c]);
            loss += 1.0f - (2.0f * iic + kEps) / (ppc + ttc + kEps);
        }
        out[0] = loss * 0.25f;
    }
}

extern "C" void kernel_launch(void* const* d_in, const int* in_sizes, int n_in,
                              void* d_out, int out_size, void* d_ws, size_t ws_size,
                              hipStream_t stream) {
    const float* in  = (const float*)d_in[0];
    const int*   tgt = (const int*)d_in[1];
    float* out = (float*)d_out;
    unsigned int* partial = (unsigned int*)d_ws;  // 12 * kBlocks uints = 48 KiB

    dice_count_kernel<<<kBlocks, kThreads, 0, stream>>>(in, tgt, partial);
    dice_final_kernel<<<1, 256, 0, stream>>>(partial, out);
}